// Round 6
// baseline (125.443 us; speedup 1.0000x reference)
//
#include <hip/hip_runtime.h>
#include <math.h>

#define NQ 20
#define OUT_DIM 512
#define FAN_IN 21     // QOUT + COND_DIM
#define BATCH 262144
#define GRID 2048     // rows/iter chip-wide = GRID*2 = 4096; 64 iterations

typedef float vfloat4 __attribute__((ext_vector_type(4)));

// ---------------------------------------------------------------------------
// Kernel 1 (1 block, 512 threads): closed-form circuit + per-column prep.
//   qout[w] = cos(p0[w])cos(p1[w]) - sin(p0[w])sin(p1[w])*CL*CR
//     (CL/CR = cos(p0[w-/+1]) interior, 1 at boundary; trailing CZ layer is
//      diagonal -> no effect on probabilities)
//   B2[j] = 2*log2(e) * (b[j] + qout . W[j,:20]);  A2[j] = 2*log2(e)*W[j,20]
// so tanh(x) = 1 - 2/(2^(fma(c,A2,B2)) + 1).
// ---------------------------------------------------------------------------
__global__ __launch_bounds__(OUT_DIM)
void prep_kernel(const float* __restrict__ params,
                 const float* __restrict__ W,
                 const float* __restrict__ b,
                 float* __restrict__ A2,
                 float* __restrict__ B2)
{
    __shared__ float qout[NQ];
    const int j = threadIdx.x;
    if (j < NQ) {
        float p0 = params[j];
        float p1 = params[NQ + j];
        float cl = (j > 0)      ? cosf(params[j - 1]) : 1.0f;
        float cr = (j < NQ - 1) ? cosf(params[j + 1]) : 1.0f;
        qout[j] = cosf(p0) * cosf(p1) - sinf(p0) * sinf(p1) * cl * cr;
    }
    __syncthreads();

    const float TWO_LOG2E = 2.8853900817779268f;  // 2*log2(e)
    const float* wr = W + j * FAN_IN;
    float acc = b[j];
#pragma unroll
    for (int k = 0; k < NQ; ++k) acc += qout[k] * wr[k];
    B2[j] = TWO_LOG2E * acc;
    A2[j] = TWO_LOG2E * wr[NQ];
}

// ---------------------------------------------------------------------------
// Kernel 2: out[i][j] = 1 - 2/(2^(fma(c_i, A2_j, B2_j)) + 1)
// GRID-STRIDE ROW MAPPING: iteration r of block b writes rows
// (r*GRID + b)*2 + {0,1}. Each grid-wide iteration covers a contiguous
// 4096-row (8 MiB) region -> single chip-wide marching write stream,
// matching the fill kernel's DRAM-row-friendly pattern.
// ---------------------------------------------------------------------------
__global__ __launch_bounds__(256)
void main_kernel(const float* __restrict__ cond,
                 const float* __restrict__ A2,
                 const float* __restrict__ B2,
                 float* __restrict__ out)
{
    const int t    = threadIdx.x;
    const int blk  = blockIdx.x;
    const int half = t >> 7;            // which row of the block's pair
    const int j    = (t & 127) << 2;    // column quad

    const vfloat4 A = *reinterpret_cast<const vfloat4*>(A2 + j);
    const vfloat4 B = *reinterpret_cast<const vfloat4*>(B2 + j);

#pragma unroll 8
    for (int r = 0; r < 64; ++r) {
        const size_t row = (size_t)(r * GRID + blk) * 2 + half;
        const float c = cond[row];       // wave-uniform, L2-resident
        vfloat4 o;
#pragma unroll
        for (int q = 0; q < 4; ++q) {
            float e = __builtin_amdgcn_exp2f(fmaf(c, A[q], B[q]));  // e^{2x}
            o[q] = fmaf(-2.0f, __builtin_amdgcn_rcpf(e + 1.0f), 1.0f);
        }
        *reinterpret_cast<vfloat4*>(out + row * OUT_DIM + j) = o;
    }
}

extern "C" void kernel_launch(void* const* d_in, const int* in_sizes, int n_in,
                              void* d_out, int out_size, void* d_ws, size_t ws_size,
                              hipStream_t stream)
{
    const float* cond   = (const float*)d_in[0];  // (BATCH, 1)
    const float* params = (const float*)d_in[1];  // (2, NQ)
    const float* W      = (const float*)d_in[2];  // (OUT_DIM, FAN_IN)
    const float* b      = (const float*)d_in[3];  // (OUT_DIM,)
    float* out = (float*)d_out;

    float* A2 = (float*)d_ws;           // OUT_DIM floats
    float* B2 = A2 + OUT_DIM;           // OUT_DIM floats

    prep_kernel<<<1, OUT_DIM, 0, stream>>>(params, W, b, A2, B2);
    main_kernel<<<GRID, 256, 0, stream>>>(cond, A2, B2, out);
}

// Round 7
// 106.467 us; speedup vs baseline: 1.1782x; 1.1782x over previous
//
#include <hip/hip_runtime.h>
#include <math.h>

#define NQ 20
#define OUT_DIM 512
#define FAN_IN 21     // QOUT + COND_DIM
#define BATCH 262144
#define GRID 2048     // 8 blocks/CU * 256 CUs; each block owns 128 contiguous rows

typedef float vfloat4 __attribute__((ext_vector_type(4)));

// ---------------------------------------------------------------------------
// Kernel 1 (1 block, 512 threads): closed-form circuit + per-column prep.
//   qout[w] = cos(p0[w])cos(p1[w]) - sin(p0[w])sin(p1[w])*CL*CR
//     (CL/CR = cos(p0[w-/+1]) interior, 1 at boundary; trailing CZ layer is
//      diagonal -> no effect on probabilities)
//   B2[j] = 2*log2(e) * (b[j] + qout . W[j,:20]);  A2[j] = 2*log2(e)*W[j,20]
// so tanh(x) = 1 - 2/(2^(fma(c,A2,B2)) + 1).
// ---------------------------------------------------------------------------
__global__ __launch_bounds__(OUT_DIM)
void prep_kernel(const float* __restrict__ params,
                 const float* __restrict__ W,
                 const float* __restrict__ b,
                 float* __restrict__ A2,
                 float* __restrict__ B2)
{
    __shared__ float qout[NQ];
    const int j = threadIdx.x;
    if (j < NQ) {
        float p0 = params[j];
        float p1 = params[NQ + j];
        float cl = (j > 0)      ? cosf(params[j - 1]) : 1.0f;
        float cr = (j < NQ - 1) ? cosf(params[j + 1]) : 1.0f;
        qout[j] = cosf(p0) * cosf(p1) - sinf(p0) * sinf(p1) * cl * cr;
    }
    __syncthreads();

    const float TWO_LOG2E = 2.8853900817779268f;  // 2*log2(e)
    const float* wr = W + j * FAN_IN;
    float acc = b[j];
#pragma unroll
    for (int k = 0; k < NQ; ++k) acc += qout[k] * wr[k];
    B2[j] = TWO_LOG2E * acc;
    A2[j] = TWO_LOG2E * wr[NQ];
}

// ---------------------------------------------------------------------------
// Kernel 2: out[i][j] = 1 - 2/(2^(fma(c_i, A2_j, B2_j)) + 1)
// R5 layout (block-private contiguous 128-row stream, LDS-staged cond),
// single change: NONTEMPORAL stores (output is write-once, never re-read;
// bypass L2 dirty-line management for the 2048 concurrent write streams).
// ---------------------------------------------------------------------------
__global__ __launch_bounds__(256)
void main_kernel(const float* __restrict__ cond,
                 const float* __restrict__ A2,
                 const float* __restrict__ B2,
                 float* __restrict__ out)
{
    __shared__ float sc[128];
    const int t    = threadIdx.x;
    const int blk  = blockIdx.x;
    const int half = t >> 7;            // which row of each pair
    const int j    = (t & 127) << 2;    // column quad

    if (t < 128) sc[t] = cond[blk * 128 + t];

    const vfloat4 A = *reinterpret_cast<const vfloat4*>(A2 + j);
    const vfloat4 B = *reinterpret_cast<const vfloat4*>(B2 + j);
    __syncthreads();

    float* p = out + (size_t)(blk * 128 + half) * OUT_DIM + j;

#pragma unroll 8
    for (int r = 0; r < 64; ++r) {
        const float c = sc[2 * r + half];   // LDS broadcast
        vfloat4 o;
#pragma unroll
        for (int q = 0; q < 4; ++q) {
            float e = __builtin_amdgcn_exp2f(fmaf(c, A[q], B[q]));  // e^{2x}
            o[q] = fmaf(-2.0f, __builtin_amdgcn_rcpf(e + 1.0f), 1.0f);
        }
        __builtin_nontemporal_store(o, reinterpret_cast<vfloat4*>(p));
        p += 2 * OUT_DIM;                   // advance 2 rows
    }
}

extern "C" void kernel_launch(void* const* d_in, const int* in_sizes, int n_in,
                              void* d_out, int out_size, void* d_ws, size_t ws_size,
                              hipStream_t stream)
{
    const float* cond   = (const float*)d_in[0];  // (BATCH, 1)
    const float* params = (const float*)d_in[1];  // (2, NQ)
    const float* W      = (const float*)d_in[2];  // (OUT_DIM, FAN_IN)
    const float* b      = (const float*)d_in[3];  // (OUT_DIM,)
    float* out = (float*)d_out;

    float* A2 = (float*)d_ws;           // OUT_DIM floats
    float* B2 = A2 + OUT_DIM;           // OUT_DIM floats

    prep_kernel<<<1, OUT_DIM, 0, stream>>>(params, W, b, A2, B2);
    main_kernel<<<GRID, 256, 0, stream>>>(cond, A2, B2, out);
}

// Round 8
// 105.763 us; speedup vs baseline: 1.1861x; 1.0067x over previous
//
#include <hip/hip_runtime.h>
#include <math.h>

#define NQ 20
#define OUT_DIM 512
#define FAN_IN 21     // QOUT + COND_DIM
#define BATCH 262144
#define GRID 1024     // 4 blocks/CU; each block owns 256 contiguous rows (512 KiB)
#define CHUNK (BATCH / GRID)   // 256 rows per block

typedef float vfloat4 __attribute__((ext_vector_type(4)));

// ---------------------------------------------------------------------------
// Kernel 1 (1 block, 512 threads): closed-form circuit + per-column prep.
//   qout[w] = cos(p0[w])cos(p1[w]) - sin(p0[w])sin(p1[w])*CL*CR
//     (CL/CR = cos(p0[w-/+1]) interior, 1 at boundary; trailing CZ layer is
//      diagonal -> no effect on probabilities)
//   B2[j] = 2*log2(e) * (b[j] + qout . W[j,:20]);  A2[j] = 2*log2(e)*W[j,20]
// so tanh(x) = 1 - 2/(2^(fma(c,A2,B2)) + 1).
// ---------------------------------------------------------------------------
__global__ __launch_bounds__(OUT_DIM)
void prep_kernel(const float* __restrict__ params,
                 const float* __restrict__ W,
                 const float* __restrict__ b,
                 float* __restrict__ A2,
                 float* __restrict__ B2)
{
    __shared__ float qout[NQ];
    const int j = threadIdx.x;
    if (j < NQ) {
        float p0 = params[j];
        float p1 = params[NQ + j];
        float cl = (j > 0)      ? cosf(params[j - 1]) : 1.0f;
        float cr = (j < NQ - 1) ? cosf(params[j + 1]) : 1.0f;
        qout[j] = cosf(p0) * cosf(p1) - sinf(p0) * sinf(p1) * cl * cr;
    }
    __syncthreads();

    const float TWO_LOG2E = 2.8853900817779268f;  // 2*log2(e)
    const float* wr = W + j * FAN_IN;
    float acc = b[j];
#pragma unroll
    for (int k = 0; k < NQ; ++k) acc += qout[k] * wr[k];
    B2[j] = TWO_LOG2E * acc;
    A2[j] = TWO_LOG2E * wr[NQ];
}

// ---------------------------------------------------------------------------
// Kernel 2: out[i][j] = 1 - 2/(2^(fma(c_i, A2_j, B2_j)) + 1)
// R5 structure; single change: GRID 2048 -> 1024 (half the concurrent DRAM
// write streams, double the per-stream length). Plain cached stores.
// ---------------------------------------------------------------------------
__global__ __launch_bounds__(256)
void main_kernel(const float* __restrict__ cond,
                 const float* __restrict__ A2,
                 const float* __restrict__ B2,
                 float* __restrict__ out)
{
    __shared__ float sc[CHUNK];
    const int t    = threadIdx.x;
    const int blk  = blockIdx.x;
    const int half = t >> 7;            // which row of each pair
    const int j    = (t & 127) << 2;    // column quad

    // stage this block's cond rows (coalesced, 256 floats)
    if (t < CHUNK) sc[t] = cond[blk * CHUNK + t];

    const vfloat4 A = *reinterpret_cast<const vfloat4*>(A2 + j);
    const vfloat4 B = *reinterpret_cast<const vfloat4*>(B2 + j);
    __syncthreads();

    float* p = out + (size_t)(blk * CHUNK + half) * OUT_DIM + j;

#pragma unroll 8
    for (int r = 0; r < CHUNK / 2; ++r) {
        const float c = sc[2 * r + half];   // LDS broadcast
        vfloat4 o;
#pragma unroll
        for (int q = 0; q < 4; ++q) {
            float e = __builtin_amdgcn_exp2f(fmaf(c, A[q], B[q]));  // e^{2x}
            o[q] = fmaf(-2.0f, __builtin_amdgcn_rcpf(e + 1.0f), 1.0f);
        }
        *reinterpret_cast<vfloat4*>(p) = o;
        p += 2 * OUT_DIM;                   // advance 2 rows
    }
}

extern "C" void kernel_launch(void* const* d_in, const int* in_sizes, int n_in,
                              void* d_out, int out_size, void* d_ws, size_t ws_size,
                              hipStream_t stream)
{
    const float* cond   = (const float*)d_in[0];  // (BATCH, 1)
    const float* params = (const float*)d_in[1];  // (2, NQ)
    const float* W      = (const float*)d_in[2];  // (OUT_DIM, FAN_IN)
    const float* b      = (const float*)d_in[3];  // (OUT_DIM,)
    float* out = (float*)d_out;

    float* A2 = (float*)d_ws;           // OUT_DIM floats
    float* B2 = A2 + OUT_DIM;           // OUT_DIM floats

    prep_kernel<<<1, OUT_DIM, 0, stream>>>(params, W, b, A2, B2);
    main_kernel<<<GRID, 256, 0, stream>>>(cond, A2, B2, out);
}

// Round 9
// 98.858 us; speedup vs baseline: 1.2689x; 1.0699x over previous
//
#include <hip/hip_runtime.h>
#include <math.h>

#define NQ 20
#define OUT_DIM 512
#define FAN_IN 21     // QOUT + COND_DIM
#define BATCH 262144
#define GRID 2048     // each block owns 128 contiguous rows (256 KiB stream)
#define CHUNK (BATCH / GRID)       // 128
#define WFLOATS (OUT_DIM * FAN_IN) // 10752 floats = 43 KB

typedef float vfloat4 __attribute__((ext_vector_type(4)));

// ---------------------------------------------------------------------------
// Single fused kernel (R5 store structure + in-block prep with COALESCED
// W staging through LDS — fixes R4's uncoalesced-W mistake).
//
//   qout[w] = cos(p0[w])cos(p1[w]) - sin(p0[w])sin(p1[w])*CL*CR   (closed
//     form; trailing CZ layer is diagonal -> no effect on probabilities)
//   B2[j] = 2*log2e*(b[j] + qout.W[j,:20]);  A2[j] = 2*log2e*W[j,20]
//   out[i][j] = 1 - 2/(2^(fma(c_i,A2_j,B2_j)) + 1)        ( = tanh )
// ---------------------------------------------------------------------------
__global__ __launch_bounds__(256)
void fused_kernel(const float* __restrict__ cond,
                  const float* __restrict__ params,
                  const float* __restrict__ W,
                  const float* __restrict__ b,
                  float* __restrict__ out)
{
    __shared__ float sW[WFLOATS];   // 43 KB, coalesced-staged copy of W
    __shared__ float qout[NQ];
    __shared__ float sc[CHUNK];

    const int t    = threadIdx.x;
    const int blk  = blockIdx.x;
    const int half = t >> 7;            // which row of each pair
    const int j    = (t & 127) << 2;    // column quad

    // stage cond rows (coalesced 512 B)
    if (t < CHUNK) sc[t] = cond[blk * CHUNK + t];

    // stage W coalesced: 2688 float4s over 256 threads
    {
        const vfloat4* Wv = reinterpret_cast<const vfloat4*>(W);
        vfloat4* sWv = reinterpret_cast<vfloat4*>(sW);
        for (int i = t; i < WFLOATS / 4; i += 256) sWv[i] = Wv[i];
    }

    // closed-form circuit output (threads 0..19)
    if (t < NQ) {
        float p0 = params[t];
        float p1 = params[NQ + t];
        float cl = (t > 0)      ? cosf(params[t - 1]) : 1.0f;
        float cr = (t < NQ - 1) ? cosf(params[t + 1]) : 1.0f;
        qout[t] = cosf(p0) * cosf(p1) - sinf(p0) * sinf(p1) * cl * cr;
    }

    const vfloat4 bb = *reinterpret_cast<const vfloat4*>(b + j);  // coalesced
    __syncthreads();

    // per-thread prep from LDS: A = 2*log2e*wlast, B = 2*log2e*base
    const float TWO_LOG2E = 2.8853900817779268f;
    vfloat4 A, B;
#pragma unroll
    for (int r = 0; r < 4; ++r) {
        const float* wr = sW + (j + r) * FAN_IN;
        float acc = bb[r];
#pragma unroll
        for (int k = 0; k < NQ; ++k) acc += qout[k] * wr[k];
        B[r] = TWO_LOG2E * acc;
        A[r] = TWO_LOG2E * wr[NQ];
    }

    float* p = out + (size_t)(blk * CHUNK + half) * OUT_DIM + j;

#pragma unroll 8
    for (int r = 0; r < CHUNK / 2; ++r) {
        const float c = sc[2 * r + half];   // LDS broadcast
        vfloat4 o;
#pragma unroll
        for (int q = 0; q < 4; ++q) {
            float e = __builtin_amdgcn_exp2f(fmaf(c, A[q], B[q]));  // e^{2x}
            o[q] = fmaf(-2.0f, __builtin_amdgcn_rcpf(e + 1.0f), 1.0f);
        }
        *reinterpret_cast<vfloat4*>(p) = o;
        p += 2 * OUT_DIM;                   // advance 2 rows
    }
}

extern "C" void kernel_launch(void* const* d_in, const int* in_sizes, int n_in,
                              void* d_out, int out_size, void* d_ws, size_t ws_size,
                              hipStream_t stream)
{
    const float* cond   = (const float*)d_in[0];  // (BATCH, 1)
    const float* params = (const float*)d_in[1];  // (2, NQ)
    const float* W      = (const float*)d_in[2];  // (OUT_DIM, FAN_IN)
    const float* b      = (const float*)d_in[3];  // (OUT_DIM,)
    float* out = (float*)d_out;

    fused_kernel<<<GRID, 256, 0, stream>>>(cond, params, W, b, out);
}